// Round 1
// 2543.319 us; speedup vs baseline: 2.0141x; 2.0141x over previous
//
#include <hip/hip_runtime.h>

#define BB 4
#define LL 2048
#define QQ 2048
#define HH 16
#define DD 64
#define EE 1024
#define NB 512

// ================= naive tiled fp32 GEMMs =================

// C[m,n] = sum_k A[m,k] * B[n,k]   (A: M x K row-major, B: N x K row-major)
__global__ __launch_bounds__(256) void nb_gemm_nt(
    const float* __restrict__ A, const float* __restrict__ B, float* __restrict__ C,
    int M, int N, int K)
{
  __shared__ float As[32][33], Bs[32][33];
  const int tid = threadIdx.x;
  const int tx = tid & 15, ty = tid >> 4;
  const int m0 = blockIdx.y * 32, n0 = blockIdx.x * 32;
  float acc00 = 0.f, acc01 = 0.f, acc10 = 0.f, acc11 = 0.f;
  for (int k0 = 0; k0 < K; k0 += 32) {
    for (int i = tid; i < 1024; i += 256) {
      int r = i >> 5, c = i & 31;
      As[r][c] = A[(long)(m0 + r) * K + k0 + c];
      Bs[r][c] = B[(long)(n0 + r) * K + k0 + c];
    }
    __syncthreads();
    #pragma unroll 8
    for (int kk = 0; kk < 32; kk++) {
      float a0 = As[ty*2][kk],   a1 = As[ty*2+1][kk];
      float b0 = Bs[tx*2][kk],   b1 = Bs[tx*2+1][kk];
      acc00 += a0*b0; acc01 += a0*b1; acc10 += a1*b0; acc11 += a1*b1;
    }
    __syncthreads();
  }
  C[(long)(m0 + ty*2    ) * N + n0 + tx*2    ] = acc00;
  C[(long)(m0 + ty*2    ) * N + n0 + tx*2 + 1] = acc01;
  C[(long)(m0 + ty*2 + 1) * N + n0 + tx*2    ] = acc10;
  C[(long)(m0 + ty*2 + 1) * N + n0 + tx*2 + 1] = acc11;
}

// C[m,n] = sum_k A[k,m] * B[k,n]   (A: K x M row-major, B: K x N row-major)
__global__ __launch_bounds__(256) void nb_gemm_tn(
    const float* __restrict__ A, const float* __restrict__ B, float* __restrict__ C,
    int M, int N, int K)
{
  __shared__ float As[32][33], Bs[32][33];   // [kk][mm] / [kk][nn]
  const int tid = threadIdx.x;
  const int tx = tid & 15, ty = tid >> 4;
  const int m0 = blockIdx.y * 32, n0 = blockIdx.x * 32;
  float acc00 = 0.f, acc01 = 0.f, acc10 = 0.f, acc11 = 0.f;
  for (int k0 = 0; k0 < K; k0 += 32) {
    for (int i = tid; i < 1024; i += 256) {
      int r = i >> 5, c = i & 31;
      As[r][c] = A[(long)(k0 + r) * M + m0 + c];
      Bs[r][c] = B[(long)(k0 + r) * N + n0 + c];
    }
    __syncthreads();
    #pragma unroll 8
    for (int kk = 0; kk < 32; kk++) {
      float a0 = As[kk][ty*2], a1 = As[kk][ty*2+1];
      float b0 = Bs[kk][tx*2], b1 = Bs[kk][tx*2+1];
      acc00 += a0*b0; acc01 += a0*b1; acc10 += a1*b0; acc11 += a1*b1;
    }
    __syncthreads();
  }
  C[(long)(m0 + ty*2    ) * N + n0 + tx*2    ] = acc00;
  C[(long)(m0 + ty*2    ) * N + n0 + tx*2 + 1] = acc01;
  C[(long)(m0 + ty*2 + 1) * N + n0 + tx*2    ] = acc10;
  C[(long)(m0 + ty*2 + 1) * N + n0 + tx*2 + 1] = acc11;
}

// ================= collapsed scores path =================
// The scores stage is linear in both qry and keys:
//   mu_logit[h,q] = (1/8) q_b[q,:] . Am[h,:]
//   Am[h,e'] = sum_d kwm[h*64+d] * Wq[h*64+d, e']
//   kwm[e]   = sum_e' Wk[e,e'] * u_mu[e']
//   u_mu[e'] = sum_n wmu[n] * Bm[n,e']
// (same chain with wsg for sigma). This removes the keys GEMM, the qry GEMM
// and the O(Q*H*NB*D) scores kernel entirely.

// u_mu/u_sg: grid(EE/256), block 256. Coalesced column reduction of Bm.
__global__ __launch_bounds__(256) void nb_uvec(
    const float* __restrict__ Bm, const float* __restrict__ wmu, const float* __restrict__ wsg,
    float* __restrict__ umu, float* __restrict__ usg)
{
  const int e = blockIdx.x * 256 + threadIdx.x;
  float am = 0.f, as = 0.f;
  #pragma unroll 8
  for (int n = 0; n < NB; n++) {
    float bv = Bm[(long)n * EE + e];
    am += wmu[n] * bv;
    as += wsg[n] * bv;
  }
  umu[e] = am; usg[e] = as;
}

// kwm/kws: grid(EE), block 256. One block per output row of Wk (coalesced row read).
__global__ __launch_bounds__(256) void nb_kw(
    const float* __restrict__ Wk, const float* __restrict__ umu, const float* __restrict__ usg,
    float* __restrict__ kwm, float* __restrict__ kws)
{
  __shared__ float pm[256], ps[256];
  const int e = blockIdx.x, t = threadIdx.x;
  const float* row = Wk + (long)e * EE;
  float am = 0.f, as = 0.f;
  #pragma unroll 4
  for (int i = t; i < EE; i += 256) {
    float w = row[i];
    am += w * umu[i];
    as += w * usg[i];
  }
  pm[t] = am; ps[t] = as;
  __syncthreads();
  for (int s = 128; s > 0; s >>= 1) {
    if (t < s) { pm[t] += pm[t + s]; ps[t] += ps[t + s]; }
    __syncthreads();
  }
  if (t == 0) { kwm[e] = pm[0]; kws[e] = ps[0]; }
}

// AmAs[e'][o]: o in [0,16) = mu head o, o in [16,32) = sigma head o-16.
// grid(EE/256, HH), block 256. Coalesced Wq row reads; transposed output so the
// consumer (nb_musig) reads AmAs coalesced across o.
__global__ __launch_bounds__(256) void nb_amas(
    const float* __restrict__ Wq, const float* __restrict__ kwm, const float* __restrict__ kws,
    float* __restrict__ AmAs)
{
  __shared__ float km[64], ks[64];
  const int t = threadIdx.x;
  const int h = blockIdx.y;
  const int e = blockIdx.x * 256 + t;
  if (t < 64) { km[t] = kwm[h * 64 + t]; ks[t] = kws[h * 64 + t]; }
  __syncthreads();
  float am = 0.f, as = 0.f;
  #pragma unroll 8
  for (int d = 0; d < 64; d++) {
    float w = Wq[(long)(h * 64 + d) * EE + e];
    am += km[d] * w;
    as += ks[d] * w;
  }
  AmAs[(long)e * 32 + h]      = am;
  AmAs[(long)e * 32 + 16 + h] = as;
}

// mu/s2: grid(QQ), block 256. Skinny [1,1024]x[1024,32] per q-row.
__global__ __launch_bounds__(256) void nb_musig(
    const float* __restrict__ qb, const float* __restrict__ AmAs,
    float* __restrict__ muq, float* __restrict__ sg2)
{
  __shared__ float qs[EE];        // 4 KB
  __shared__ float part[8][32];
  const int t = threadIdx.x, qrow = blockIdx.x;
  for (int i = t; i < EE; i += 256) qs[i] = qb[(long)qrow * EE + i];
  __syncthreads();
  const int o = t & 31, ch = t >> 5;        // 8 chunks of 128 e'
  float acc = 0.f;
  const int e0 = ch * 128;
  #pragma unroll 8
  for (int i = 0; i < 128; i++) {
    int e = e0 + i;
    acc += qs[e] * AmAs[(long)e * 32 + o];  // coalesced across o, qs broadcast
  }
  part[ch][o] = acc;
  __syncthreads();
  if (t < 32) {
    float s = 0.f;
    #pragma unroll
    for (int c = 0; c < 8; c++) s += part[c][o];
    s *= 0.125f;                             // /sqrt(64)
    if (o < 16) {
      muq[(long)o * QQ + qrow] = 1.f / (1.f + expf(-s));
    } else {
      float sp = (s > 20.f) ? s : log1pf(expf(s));
      sg2[(long)(o - 16) * QQ + qrow] = fmaxf(sp, 1e-4f);
    }
  }
}

// ================= ctx (one block per q): r on the fly, flat vals [n][e] ================
__global__ __launch_bounds__(256) void nb_ctx(
    const float* __restrict__ vals, const float* __restrict__ muq, const float* __restrict__ sg2,
    const float* __restrict__ bmu,  const float* __restrict__ bsg, float* __restrict__ ctx)
{
  __shared__ float rbuf[HH * NB];     // 16*512 fp32 = 32 KB
  __shared__ float muh[HH], s2h[HH];
  const int t = threadIdx.x;
  const int qrow = blockIdx.x;
  if (t < HH) {
    muh[t] = muq[(long)t * QQ + qrow];
    s2h[t] = sg2[(long)t * QQ + qrow];
  }
  __syncthreads();
  for (int idx = t; idx < HH * NB; idx += 256) {
    int h = idx >> 9, n = idx & 511;
    float tt = muh[h] - bmu[n];
    float v  = s2h[h] + bsg[n] * bsg[n];
    rbuf[idx] = expf(-0.5f * tt * tt / v) / sqrtf(6.283185307179586f * v);
  }
  __syncthreads();
  #pragma unroll
  for (int i = 0; i < 4; i++) {
    int e = i * 256 + t;
    int h = e >> 6;
    const float* rp = rbuf + h * NB;
    float acc = 0.f;
    for (int n = 0; n < NB; n++) acc += rp[n] * vals[(long)n * EE + e];
    ctx[(long)qrow * EE + e] = acc;
  }
}

extern "C" void kernel_launch(void* const* d_in, const int* in_sizes, int n_in,
                              void* d_out, int out_size, void* d_ws, size_t ws_size,
                              hipStream_t stream) {
  const float* k   = (const float*)d_in[0];
  const float* q   = (const float*)d_in[1];
  const float* Wq  = (const float*)d_in[2];
  const float* Wk  = (const float*)d_in[3];
  const float* Wv  = (const float*)d_in[4];
  const float* Wo  = (const float*)d_in[5];
  const float* wmu = (const float*)d_in[6];
  const float* wsg = (const float*)d_in[7];
  const float* Gs  = (const float*)d_in[8];
  const float* bmu = (const float*)d_in[9];
  const float* bsg = (const float*)d_in[10];
  float* out = (float*)d_out;

  // Per-batch ws overlay, TOTAL 14 MiB:
  //   Bm_b   [0.0, 2.0) MiB   fp32 [512][1024]
  //   vals_b [2.0, 4.0) MiB   fp32 [512][1024] flat (h folded into e)
  //   muq_b  [4.0, 4.125) MiB fp32 [16][2048]
  //   sg2_b  [4.125, 4.25)    fp32 [16][2048]
  //   umu/usg/kwm/kws  at 4.25 MiB, 4 KiB each
  //   AmAs   [4.5, 4.625) MiB fp32 [1024][32]
  //   ctx_b  [6.0, 14.0) MiB  fp32 [2048][1024]
  char* ws = (char*)d_ws;
  float* Bm_b   = (float*)(ws + 0);
  float* vals_b = (float*)(ws + (2u  << 20));
  float* muq_b  = (float*)(ws + (4u  << 20));
  float* sg2_b  = (float*)(ws + (4u  << 20) + (128u << 10));
  float* umu_b  = (float*)(ws + (4u  << 20) + (256u << 10));
  float* usg_b  = (float*)(ws + (4u  << 20) + (260u << 10));
  float* kwm_b  = (float*)(ws + (4u  << 20) + (264u << 10));
  float* kws_b  = (float*)(ws + (4u  << 20) + (268u << 10));
  float* AmAs_b = (float*)(ws + (4u  << 20) + (512u << 10));
  float* ctx_b  = (float*)(ws + (6u  << 20));

  for (int b = 0; b < BB; b++) {
    const float* k_b = k + (long)b * LL * EE;
    const float* q_b = q + (long)b * QQ * EE;
    float*       o_b = out + (long)b * QQ * EE;
    // st2: Bm_b[nb][e] = sum_l Gs[l][nb] * k_b[l][e]
    nb_gemm_tn<<<dim3(EE/32, NB/32), 256, 0, stream>>>(Gs, k_b, Bm_b, NB, EE, LL);
    // st3: vals_b[nb][e] = sum_e' Bm_b[nb][e'] * Wv[e][e']
    nb_gemm_nt<<<dim3(EE/32, NB/32), 256, 0, stream>>>(Bm_b, Wv, vals_b, NB, EE, EE);
    // st4: collapsed scores path (replaces keys GEMM + qry GEMM + nb_scores)
    nb_uvec <<<dim3(EE/256),      256, 0, stream>>>(Bm_b, wmu, wsg, umu_b, usg_b);
    nb_kw   <<<dim3(EE),          256, 0, stream>>>(Wk, umu_b, usg_b, kwm_b, kws_b);
    nb_amas <<<dim3(EE/256, HH),  256, 0, stream>>>(Wq, kwm_b, kws_b, AmAs_b);
    nb_musig<<<dim3(QQ),          256, 0, stream>>>(q_b, AmAs_b, muq_b, sg2_b);
    // st6: ctx_b[q][e]
    nb_ctx<<<dim3(QQ), 256, 0, stream>>>(vals_b, muq_b, sg2_b, bmu, bsg, ctx_b);
    // st7: out_b[q][e] = sum_e' ctx_b[q][e'] * Wo[e][e']
    nb_gemm_nt<<<dim3(EE/32, QQ/32), 256, 0, stream>>>(ctx_b, Wo, o_b, QQ, EE, EE);
  }
  (void)in_sizes; (void)n_in; (void)out_size; (void)ws_size;
}

// Round 2
// 930.694 us; speedup vs baseline: 5.5040x; 2.7327x over previous
//
#include <hip/hip_runtime.h>

#define BB 4
#define LL 2048
#define QQ 2048
#define HH 16
#define DD 64
#define EE 1024
#define NB 512

// ================= 64x64-tile fp32 GEMMs, 256 thr, 4x4 microtile =================
// LDS layout is K-major [k][m] so the inner loop does float4 LDS reads
// (a: 4 distinct addrs/wave -> broadcast; b: 16 distinct float4 = 2-way = free).

// C[m,n] = sum_k A[m,k] * B[n,k]   (A: M x K, B: N x K, row-major)
__global__ __launch_bounds__(256) void gemm_nt64(
    const float* __restrict__ A, const float* __restrict__ B, float* __restrict__ C,
    int M, int N, int K, long sA, long sB, long sC)
{
  A += (long)blockIdx.z * sA; B += (long)blockIdx.z * sB; C += (long)blockIdx.z * sC;
  __shared__ float As[32][68], Bs[32][68];   // [k][m], [k][n]
  const int t = threadIdx.x;
  const int tx = t & 15, ty = t >> 4;
  const int m0 = blockIdx.y * 64, n0 = blockIdx.x * 64;
  float acc[4][4] = {};
  for (int k0 = 0; k0 < K; k0 += 32) {
    #pragma unroll
    for (int i = 0; i < 2; i++) {
      int f = t + i * 256;
      int r = f >> 3, k4 = f & 7;            // r: row in tile, k4: float4 along K
      float4 va = *(const float4*)&A[(long)(m0 + r) * K + k0 + k4 * 4];
      As[k4*4+0][r] = va.x; As[k4*4+1][r] = va.y; As[k4*4+2][r] = va.z; As[k4*4+3][r] = va.w;
      float4 vb = *(const float4*)&B[(long)(n0 + r) * K + k0 + k4 * 4];
      Bs[k4*4+0][r] = vb.x; Bs[k4*4+1][r] = vb.y; Bs[k4*4+2][r] = vb.z; Bs[k4*4+3][r] = vb.w;
    }
    __syncthreads();
    #pragma unroll
    for (int kk = 0; kk < 32; kk++) {
      float4 a4 = *(const float4*)&As[kk][ty * 4];
      float4 b4 = *(const float4*)&Bs[kk][tx * 4];
      float ar[4] = {a4.x, a4.y, a4.z, a4.w};
      float br[4] = {b4.x, b4.y, b4.z, b4.w};
      #pragma unroll
      for (int i = 0; i < 4; i++)
        #pragma unroll
        for (int j = 0; j < 4; j++)
          acc[i][j] += ar[i] * br[j];
    }
    __syncthreads();
  }
  #pragma unroll
  for (int i = 0; i < 4; i++) {
    float4 o = make_float4(acc[i][0], acc[i][1], acc[i][2], acc[i][3]);
    *(float4*)&C[(long)(m0 + ty*4 + i) * N + n0 + tx*4] = o;
  }
}

// C[m,n] = sum_k A[k,m] * B[k,n]   (A: K x M, B: K x N, row-major)
__global__ __launch_bounds__(256) void gemm_tn64(
    const float* __restrict__ A, const float* __restrict__ B, float* __restrict__ C,
    int M, int N, int K, long sA, long sB, long sC)
{
  A += (long)blockIdx.z * sA; B += (long)blockIdx.z * sB; C += (long)blockIdx.z * sC;
  __shared__ float As[32][68], Bs[32][68];
  const int t = threadIdx.x;
  const int tx = t & 15, ty = t >> 4;
  const int m0 = blockIdx.y * 64, n0 = blockIdx.x * 64;
  float acc[4][4] = {};
  for (int k0 = 0; k0 < K; k0 += 32) {
    #pragma unroll
    for (int i = 0; i < 2; i++) {
      int f = t + i * 256;
      int r = f >> 4, c4 = f & 15;           // r: k-row, c4: float4 along M/N
      *(float4*)&As[r][c4 * 4] = *(const float4*)&A[(long)(k0 + r) * M + m0 + c4 * 4];
      *(float4*)&Bs[r][c4 * 4] = *(const float4*)&B[(long)(k0 + r) * N + n0 + c4 * 4];
    }
    __syncthreads();
    #pragma unroll
    for (int kk = 0; kk < 32; kk++) {
      float4 a4 = *(const float4*)&As[kk][ty * 4];
      float4 b4 = *(const float4*)&Bs[kk][tx * 4];
      float ar[4] = {a4.x, a4.y, a4.z, a4.w};
      float br[4] = {b4.x, b4.y, b4.z, b4.w};
      #pragma unroll
      for (int i = 0; i < 4; i++)
        #pragma unroll
        for (int j = 0; j < 4; j++)
          acc[i][j] += ar[i] * br[j];
    }
    __syncthreads();
  }
  #pragma unroll
  for (int i = 0; i < 4; i++) {
    float4 o = make_float4(acc[i][0], acc[i][1], acc[i][2], acc[i][3]);
    *(float4*)&C[(long)(m0 + ty*4 + i) * N + n0 + tx*4] = o;
  }
}

// ================= collapsed scores path (linear in qry and keys) =================
//   mu_logit[h,q] = (1/8) q_b[q,:] . Am[h,:]
//   Am[h,e'] = sum_d kwm[h*64+d]*Wq[h*64+d,e'];  kwm = Wk @ u;  u = wmu^T @ Bm

// partial u vectors: grid(EE/256, 8 chunks, B). ump[c][e] = sum_{n in chunk c} wmu[n]*Bm[n][e]
__global__ __launch_bounds__(256) void nb_uvec(
    const float* __restrict__ Bm, const float* __restrict__ wmu, const float* __restrict__ wsg,
    float* __restrict__ ump, float* __restrict__ usp, long sBm, long sU)
{
  Bm += (long)blockIdx.z * sBm; ump += (long)blockIdx.z * sU; usp += (long)blockIdx.z * sU;
  const int e = blockIdx.x * 256 + threadIdx.x;
  const int c = blockIdx.y;
  float am = 0.f, as = 0.f;
  #pragma unroll 8
  for (int n = c * 64; n < c * 64 + 64; n++) {
    float bv = Bm[(long)n * EE + e];
    am += wmu[n] * bv;
    as += wsg[n] * bv;
  }
  ump[(long)c * EE + e] = am;
  usp[(long)c * EE + e] = as;
}

// kwm/kws: one block per output row of Wk; folds the 8-way partial sum inline.
__global__ __launch_bounds__(256) void nb_kw(
    const float* __restrict__ Wk, const float* __restrict__ ump, const float* __restrict__ usp,
    float* __restrict__ kwm, float* __restrict__ kws, long sU, long sK)
{
  ump += (long)blockIdx.z * sU; usp += (long)blockIdx.z * sU;
  kwm += (long)blockIdx.z * sK; kws += (long)blockIdx.z * sK;
  __shared__ float pm[256], ps[256];
  const int e = blockIdx.x, t = threadIdx.x;
  const float* row = Wk + (long)e * EE;
  float am = 0.f, as = 0.f;
  for (int i = t; i < EE; i += 256) {
    float um = 0.f, us = 0.f;
    #pragma unroll
    for (int c = 0; c < 8; c++) { um += ump[(long)c * EE + i]; us += usp[(long)c * EE + i]; }
    float w = row[i];
    am += w * um;
    as += w * us;
  }
  pm[t] = am; ps[t] = as;
  __syncthreads();
  for (int s = 128; s > 0; s >>= 1) {
    if (t < s) { pm[t] += pm[t + s]; ps[t] += ps[t + s]; }
    __syncthreads();
  }
  if (t == 0) { kwm[e] = pm[0]; kws[e] = ps[0]; }
}

// AmAs[e'][o]: o in [0,16) mu head o, [16,32) sigma head o-16. grid(EE/256, HH, B).
__global__ __launch_bounds__(256) void nb_amas(
    const float* __restrict__ Wq, const float* __restrict__ kwm, const float* __restrict__ kws,
    float* __restrict__ AmAs, long sK, long sAm)
{
  kwm += (long)blockIdx.z * sK; kws += (long)blockIdx.z * sK;
  AmAs += (long)blockIdx.z * sAm;
  __shared__ float km[64], ks[64];
  const int t = threadIdx.x;
  const int h = blockIdx.y;
  const int e = blockIdx.x * 256 + t;
  if (t < 64) { km[t] = kwm[h * 64 + t]; ks[t] = kws[h * 64 + t]; }
  __syncthreads();
  float am = 0.f, as = 0.f;
  #pragma unroll 8
  for (int d = 0; d < 64; d++) {
    float w = Wq[(long)(h * 64 + d) * EE + e];
    am += km[d] * w;
    as += ks[d] * w;
  }
  AmAs[(long)e * 32 + h]      = am;
  AmAs[(long)e * 32 + 16 + h] = as;
}

// mu/s2: grid(QQ, 1, B). Skinny [1,1024]x[1024,32] per q-row.
__global__ __launch_bounds__(256) void nb_musig(
    const float* __restrict__ qb, const float* __restrict__ AmAs,
    float* __restrict__ muq, float* __restrict__ sg2, long sQ, long sAm, long sMu)
{
  qb += (long)blockIdx.z * sQ; AmAs += (long)blockIdx.z * sAm;
  muq += (long)blockIdx.z * sMu; sg2 += (long)blockIdx.z * sMu;
  __shared__ float qs[EE];
  __shared__ float part[8][32];
  const int t = threadIdx.x, qrow = blockIdx.x;
  for (int i = t; i < EE; i += 256) qs[i] = qb[(long)qrow * EE + i];
  __syncthreads();
  const int o = t & 31, ch = t >> 5;
  float acc = 0.f;
  const int e0 = ch * 128;
  #pragma unroll 8
  for (int i = 0; i < 128; i++) {
    int e = e0 + i;
    acc += qs[e] * AmAs[(long)e * 32 + o];
  }
  part[ch][o] = acc;
  __syncthreads();
  if (t < 32) {
    float s = 0.f;
    #pragma unroll
    for (int c = 0; c < 8; c++) s += part[c][o];
    s *= 0.125f;
    if (o < 16) {
      muq[(long)o * QQ + qrow] = 1.f / (1.f + expf(-s));
    } else {
      float sp = (s > 20.f) ? s : log1pf(expf(s));
      sg2[(long)(o - 16) * QQ + qrow] = fmaxf(sp, 1e-4f);
    }
  }
}

// ================= ctx as 64x64 GEMM with computed A-tile (r^T) =================
// block (q-tile, h): ctx[q0:q0+64, h*64:(h+1)*64] = r[q0:q0+64, :] @ vals[:, h*64:(h+1)*64]
__global__ __launch_bounds__(256) void nb_ctx64(
    const float* __restrict__ vals, const float* __restrict__ muq, const float* __restrict__ sg2,
    const float* __restrict__ bmu,  const float* __restrict__ bsg, float* __restrict__ ctx)
{
  __shared__ float As[32][68], Bs[32][68];   // As: [n][q] = r^T chunk, Bs: [n][e]
  __shared__ float mu_s[64], s2_s[64];
  const int t = threadIdx.x;
  const int tx = t & 15, ty = t >> 4;
  const int q0 = blockIdx.x * 64;
  const int h  = blockIdx.y;
  if (t < 64) {
    mu_s[t] = muq[(long)h * QQ + q0 + t];
    s2_s[t] = sg2[(long)h * QQ + q0 + t];
  }
  __syncthreads();
  float acc[4][4] = {};
  for (int n0 = 0; n0 < NB; n0 += 32) {
    // stage vals chunk
    #pragma unroll
    for (int i = 0; i < 2; i++) {
      int f = t + i * 256;
      int r = f >> 4, c4 = f & 15;
      *(float4*)&Bs[r][c4 * 4] = *(const float4*)&vals[(long)(n0 + r) * EE + h * 64 + c4 * 4];
    }
    // compute r^T chunk: 2048 values, 8 per thread; lanes write consecutive q -> conflict-free
    #pragma unroll
    for (int i = 0; i < 8; i++) {
      int idx = t + i * 256;
      int n = idx >> 6, qq = idx & 63;
      float bm = bmu[n0 + n], bs = bsg[n0 + n];
      float v = s2_s[qq] + bs * bs;
      float d = mu_s[qq] - bm;
      As[n][qq] = expf(-0.5f * d * d / v) / sqrtf(6.283185307179586f * v);
    }
    __syncthreads();
    #pragma unroll
    for (int kk = 0; kk < 32; kk++) {
      float4 a4 = *(const float4*)&As[kk][ty * 4];
      float4 b4 = *(const float4*)&Bs[kk][tx * 4];
      float ar[4] = {a4.x, a4.y, a4.z, a4.w};
      float br[4] = {b4.x, b4.y, b4.z, b4.w};
      #pragma unroll
      for (int i = 0; i < 4; i++)
        #pragma unroll
        for (int j = 0; j < 4; j++)
          acc[i][j] += ar[i] * br[j];
    }
    __syncthreads();
  }
  #pragma unroll
  for (int i = 0; i < 4; i++) {
    float4 o = make_float4(acc[i][0], acc[i][1], acc[i][2], acc[i][3]);
    *(float4*)&ctx[(long)(q0 + ty*4 + i) * EE + h * 64 + tx*4] = o;
  }
}

extern "C" void kernel_launch(void* const* d_in, const int* in_sizes, int n_in,
                              void* d_out, int out_size, void* d_ws, size_t ws_size,
                              hipStream_t stream) {
  const float* k   = (const float*)d_in[0];
  const float* q   = (const float*)d_in[1];
  const float* Wq  = (const float*)d_in[2];
  const float* Wk  = (const float*)d_in[3];
  const float* Wv  = (const float*)d_in[4];
  const float* Wo  = (const float*)d_in[5];
  const float* wmu = (const float*)d_in[6];
  const float* wsg = (const float*)d_in[7];
  const float* Gs  = (const float*)d_in[8];
  const float* bmu = (const float*)d_in[9];
  const float* bsg = (const float*)d_in[10];
  float* out = (float*)d_out;
  char* ws = (char*)d_ws;

  const long sBm = (long)NB * EE;      // 512K elems = 2 MiB
  const long sU  = 8L * EE;
  const long sK  = EE;
  const long sAm = 32L * EE;
  const long sMu = (long)HH * QQ;
  const long sQ  = (long)QQ * EE;

  if (ws_size >= (26u << 20)) {
    // ---- batched path: fill all 256 CUs on the small GEMMs ----
    // layout: Bm4 [0,8) MiB | vals4 [8,16) | ctx scratch [16,24) | smalls [24,26)
    float* Bm4   = (float*)(ws + 0);
    float* vals4 = (float*)(ws + (8u  << 20));
    float* ctxS  = (float*)(ws + (16u << 20));
    float* ump4  = (float*)(ws + (24u << 20));                    // 4 x 32 KiB
    float* usp4  = (float*)(ws + (24u << 20) + (128u << 10));
    float* kwm4  = (float*)(ws + (24u << 20) + (256u << 10));     // 4 x 4 KiB
    float* kws4  = (float*)(ws + (24u << 20) + (272u << 10));
    float* AmAs4 = (float*)(ws + (24u << 20) + (512u << 10));     // 4 x 128 KiB
    float* muq4  = (float*)(ws + (25u << 20));                    // 4 x 128 KiB
    float* sg24  = (float*)(ws + (25u << 20) + (512u << 10));

    gemm_tn64<<<dim3(EE/64, NB/64, BB), 256, 0, stream>>>(Gs, k, Bm4, NB, EE, LL, 0L, (long)LL*EE, sBm);
    gemm_nt64<<<dim3(EE/64, NB/64, BB), 256, 0, stream>>>(Bm4, Wv, vals4, NB, EE, EE, sBm, 0L, sBm);
    nb_uvec  <<<dim3(EE/256, 8, BB),   256, 0, stream>>>(Bm4, wmu, wsg, ump4, usp4, sBm, sU);
    nb_kw    <<<dim3(EE, 1, BB),       256, 0, stream>>>(Wk, ump4, usp4, kwm4, kws4, sU, sK);
    nb_amas  <<<dim3(EE/256, HH, BB),  256, 0, stream>>>(Wq, kwm4, kws4, AmAs4, sK, sAm);
    nb_musig <<<dim3(QQ, 1, BB),       256, 0, stream>>>(q, AmAs4, muq4, sg24, sQ, sAm, sMu);
    for (int b = 0; b < BB; b++) {
      nb_ctx64<<<dim3(QQ/64, HH), 256, 0, stream>>>(vals4 + (long)b*sBm, muq4 + (long)b*sMu,
                                                    sg24 + (long)b*sMu, bmu, bsg, ctxS);
      gemm_nt64<<<dim3(EE/64, QQ/64, 1), 256, 0, stream>>>(ctxS, Wo, out + (long)b*sQ,
                                                           QQ, EE, EE, 0L, 0L, 0L);
    }
  } else {
    // ---- fallback per-batch path (12.5 MiB) ----
    float* Bm_b   = (float*)(ws + 0);
    float* vals_b = (float*)(ws + (2u  << 20));
    float* ctxS   = (float*)(ws + (4u  << 20));
    float* ump_b  = (float*)(ws + (12u << 20));
    float* usp_b  = (float*)(ws + (12u << 20) + (32u  << 10));
    float* kwm_b  = (float*)(ws + (12u << 20) + (64u  << 10));
    float* kws_b  = (float*)(ws + (12u << 20) + (68u  << 10));
    float* AmAs_b = (float*)(ws + (12u << 20) + (128u << 10));
    float* muq_b  = (float*)(ws + (12u << 20) + (256u << 10));
    float* sg2_b  = (float*)(ws + (12u << 20) + (384u << 10));

    for (int b = 0; b < BB; b++) {
      const float* k_b = k + (long)b * LL * EE;
      const float* q_b = q + (long)b * sQ;
      float*       o_b = out + (long)b * sQ;
      gemm_tn64<<<dim3(EE/64, NB/64, 1), 256, 0, stream>>>(Gs, k_b, Bm_b, NB, EE, LL, 0L, 0L, 0L);
      gemm_nt64<<<dim3(EE/64, NB/64, 1), 256, 0, stream>>>(Bm_b, Wv, vals_b, NB, EE, EE, 0L, 0L, 0L);
      nb_uvec  <<<dim3(EE/256, 8, 1),   256, 0, stream>>>(Bm_b, wmu, wsg, ump_b, usp_b, 0L, 0L);
      nb_kw    <<<dim3(EE, 1, 1),       256, 0, stream>>>(Wk, ump_b, usp_b, kwm_b, kws_b, 0L, 0L);
      nb_amas  <<<dim3(EE/256, HH, 1),  256, 0, stream>>>(Wq, kwm_b, kws_b, AmAs_b, 0L, 0L);
      nb_musig <<<dim3(QQ, 1, 1),       256, 0, stream>>>(q_b, AmAs_b, muq_b, sg2_b, 0L, 0L, 0L);
      nb_ctx64 <<<dim3(QQ/64, HH),      256, 0, stream>>>(vals_b, muq_b, sg2_b, bmu, bsg, ctxS);
      gemm_nt64<<<dim3(EE/64, QQ/64, 1), 256, 0, stream>>>(ctxS, Wo, o_b, QQ, EE, EE, 0L, 0L, 0L);
    }
  }
  (void)in_sizes; (void)n_in; (void)out_size;
}

// Round 3
// 791.005 us; speedup vs baseline: 6.4759x; 1.1766x over previous
//
#include <hip/hip_runtime.h>

#define BB 4
#define LL 2048
#define QQ 2048
#define HH 16
#define DD 64
#define EE 1024
#define NB 512

// ---------- dst[z] = src[2z] + src[2z+1]  (slab pair reduce; in-place safe) ----------
__global__ __launch_bounds__(256) void add_pairs(
    float* __restrict__ dst, long dstStride,
    const float* __restrict__ src, long srcPairStride, long n)
{
  float* d = dst + (long)blockIdx.z * dstStride;
  const float* s0 = src + (long)blockIdx.z * srcPairStride;
  const float* s1 = s0 + n;
  long i0 = ((long)blockIdx.x * 256 + threadIdx.x) * 4;
  long stride = (long)gridDim.x * 1024;
  for (long i = i0; i < n; i += stride) {
    float4 a = *(const float4*)&s0[i];
    float4 b = *(const float4*)&s1[i];
    a.x += b.x; a.y += b.y; a.z += b.z; a.w += b.w;
    *(float4*)&d[i] = a;
  }
}

// ================= 128x128-tile fp32 GEMMs, 256 thr, 8x8 microtile, split-K =================
// LDS [k][m] K-major, pad to 132 floats. 4 ds_read_b128 per 64 FMA per kk.

// C[z][m,n] = sum_{k in chunk ks} A[m,k]*B[n,k]; z = b*NS+ks
__global__ __launch_bounds__(256) void gemm_nt128(
    const float* __restrict__ A, const float* __restrict__ B, float* __restrict__ C,
    int N, int K, long sA, long sB, long sC, int NS, int Kc)
{
  const int z = blockIdx.z;
  const int b = z / NS, ks = z - b * NS;
  A += (long)b * sA + (long)ks * Kc;
  B += (long)b * sB + (long)ks * Kc;
  C += (long)z * sC;
  __shared__ float As[32][132], Bs[32][132];
  const int t = threadIdx.x;
  const int tx = t & 15, ty = t >> 4;
  const long m0 = (long)blockIdx.y * 128, n0 = (long)blockIdx.x * 128;
  float acc[8][8] = {};
  for (int k0 = 0; k0 < Kc; k0 += 32) {
    #pragma unroll
    for (int i = 0; i < 4; i++) {
      int f = t + i * 256;               // 0..1023
      int r = f >> 3, k4 = f & 7;        // row 0..127, k-quad 0..7
      float4 va = *(const float4*)&A[(m0 + r) * K + k0 + k4 * 4];
      As[k4*4+0][r] = va.x; As[k4*4+1][r] = va.y; As[k4*4+2][r] = va.z; As[k4*4+3][r] = va.w;
      float4 vb = *(const float4*)&B[(n0 + r) * K + k0 + k4 * 4];
      Bs[k4*4+0][r] = vb.x; Bs[k4*4+1][r] = vb.y; Bs[k4*4+2][r] = vb.z; Bs[k4*4+3][r] = vb.w;
    }
    __syncthreads();
    #pragma unroll
    for (int kk = 0; kk < 32; kk++) {
      float4 a0 = *(const float4*)&As[kk][ty*8];
      float4 a1 = *(const float4*)&As[kk][ty*8+4];
      float4 b0 = *(const float4*)&Bs[kk][tx*8];
      float4 b1 = *(const float4*)&Bs[kk][tx*8+4];
      float ar[8] = {a0.x,a0.y,a0.z,a0.w,a1.x,a1.y,a1.z,a1.w};
      float br[8] = {b0.x,b0.y,b0.z,b0.w,b1.x,b1.y,b1.z,b1.w};
      #pragma unroll
      for (int i = 0; i < 8; i++)
        #pragma unroll
        for (int j = 0; j < 8; j++)
          acc[i][j] += ar[i] * br[j];
    }
    __syncthreads();
  }
  #pragma unroll
  for (int i = 0; i < 8; i++) {
    float4 o0 = make_float4(acc[i][0], acc[i][1], acc[i][2], acc[i][3]);
    float4 o1 = make_float4(acc[i][4], acc[i][5], acc[i][6], acc[i][7]);
    *(float4*)&C[(m0 + ty*8 + i) * N + n0 + tx*8    ] = o0;
    *(float4*)&C[(m0 + ty*8 + i) * N + n0 + tx*8 + 4] = o1;
  }
}

// C[z][m,n] = sum_{k in chunk} A[k,m]*B[k,n]; A: KxM row-major, B: KxN row-major
__global__ __launch_bounds__(256) void gemm_tn128(
    const float* __restrict__ A, const float* __restrict__ B, float* __restrict__ C,
    int M, int N, long sA, long sB, long sC, int NS, int Kc)
{
  const int z = blockIdx.z;
  const int b = z / NS, ks = z - b * NS;
  A += (long)b * sA + (long)ks * Kc * M;
  B += (long)b * sB + (long)ks * Kc * N;
  C += (long)z * sC;
  __shared__ float As[32][132], Bs[32][132];
  const int t = threadIdx.x;
  const int tx = t & 15, ty = t >> 4;
  const long m0 = (long)blockIdx.y * 128, n0 = (long)blockIdx.x * 128;
  float acc[8][8] = {};
  for (int k0 = 0; k0 < Kc; k0 += 32) {
    #pragma unroll
    for (int i = 0; i < 4; i++) {
      int f = t + i * 256;               // 0..1023 = 32 k-rows x 32 f4
      int r = f >> 5, c4 = f & 31;
      *(float4*)&As[r][c4 * 4] = *(const float4*)&A[(long)(k0 + r) * M + m0 + c4 * 4];
      *(float4*)&Bs[r][c4 * 4] = *(const float4*)&B[(long)(k0 + r) * N + n0 + c4 * 4];
    }
    __syncthreads();
    #pragma unroll
    for (int kk = 0; kk < 32; kk++) {
      float4 a0 = *(const float4*)&As[kk][ty*8];
      float4 a1 = *(const float4*)&As[kk][ty*8+4];
      float4 b0 = *(const float4*)&Bs[kk][tx*8];
      float4 b1 = *(const float4*)&Bs[kk][tx*8+4];
      float ar[8] = {a0.x,a0.y,a0.z,a0.w,a1.x,a1.y,a1.z,a1.w};
      float br[8] = {b0.x,b0.y,b0.z,b0.w,b1.x,b1.y,b1.z,b1.w};
      #pragma unroll
      for (int i = 0; i < 8; i++)
        #pragma unroll
        for (int j = 0; j < 8; j++)
          acc[i][j] += ar[i] * br[j];
    }
    __syncthreads();
  }
  #pragma unroll
  for (int i = 0; i < 8; i++) {
    float4 o0 = make_float4(acc[i][0], acc[i][1], acc[i][2], acc[i][3]);
    float4 o1 = make_float4(acc[i][4], acc[i][5], acc[i][6], acc[i][7]);
    *(float4*)&C[(m0 + ty*8 + i) * N + n0 + tx*8    ] = o0;
    *(float4*)&C[(m0 + ty*8 + i) * N + n0 + tx*8 + 4] = o1;
  }
}

// 64x64/4x4 NT GEMM kept for tier-2 per-batch st7 (512 blocks beats half-idle 128-tile)
__global__ __launch_bounds__(256) void gemm_nt64(
    const float* __restrict__ A, const float* __restrict__ B, float* __restrict__ C,
    int M, int N, int K, long sA, long sB, long sC)
{
  A += (long)blockIdx.z * sA; B += (long)blockIdx.z * sB; C += (long)blockIdx.z * sC;
  __shared__ float As[32][68], Bs[32][68];
  const int t = threadIdx.x;
  const int tx = t & 15, ty = t >> 4;
  const int m0 = blockIdx.y * 64, n0 = blockIdx.x * 64;
  float acc[4][4] = {};
  for (int k0 = 0; k0 < K; k0 += 32) {
    #pragma unroll
    for (int i = 0; i < 2; i++) {
      int f = t + i * 256;
      int r = f >> 3, k4 = f & 7;
      float4 va = *(const float4*)&A[(long)(m0 + r) * K + k0 + k4 * 4];
      As[k4*4+0][r] = va.x; As[k4*4+1][r] = va.y; As[k4*4+2][r] = va.z; As[k4*4+3][r] = va.w;
      float4 vb = *(const float4*)&B[(long)(n0 + r) * K + k0 + k4 * 4];
      Bs[k4*4+0][r] = vb.x; Bs[k4*4+1][r] = vb.y; Bs[k4*4+2][r] = vb.z; Bs[k4*4+3][r] = vb.w;
    }
    __syncthreads();
    #pragma unroll
    for (int kk = 0; kk < 32; kk++) {
      float4 a4 = *(const float4*)&As[kk][ty * 4];
      float4 b4 = *(const float4*)&Bs[kk][tx * 4];
      float ar[4] = {a4.x, a4.y, a4.z, a4.w};
      float br[4] = {b4.x, b4.y, b4.z, b4.w};
      #pragma unroll
      for (int i = 0; i < 4; i++)
        #pragma unroll
        for (int j = 0; j < 4; j++)
          acc[i][j] += ar[i] * br[j];
    }
    __syncthreads();
  }
  #pragma unroll
  for (int i = 0; i < 4; i++) {
    float4 o = make_float4(acc[i][0], acc[i][1], acc[i][2], acc[i][3]);
    *(float4*)&C[(long)(m0 + ty*4 + i) * N + n0 + tx*4] = o;
  }
}

// ================= collapsed scores path (linear in qry and keys) =================
__global__ __launch_bounds__(256) void nb_uvec(
    const float* __restrict__ Bm, const float* __restrict__ wmu, const float* __restrict__ wsg,
    float* __restrict__ ump, float* __restrict__ usp, long sBm, long sU)
{
  Bm += (long)blockIdx.z * sBm; ump += (long)blockIdx.z * sU; usp += (long)blockIdx.z * sU;
  const int e = blockIdx.x * 256 + threadIdx.x;
  const int c = blockIdx.y;
  float am = 0.f, as = 0.f;
  #pragma unroll 8
  for (int n = c * 64; n < c * 64 + 64; n++) {
    float bv = Bm[(long)n * EE + e];
    am += wmu[n] * bv;
    as += wsg[n] * bv;
  }
  ump[(long)c * EE + e] = am;
  usp[(long)c * EE + e] = as;
}

__global__ __launch_bounds__(256) void nb_kw(
    const float* __restrict__ Wk, const float* __restrict__ ump, const float* __restrict__ usp,
    float* __restrict__ kwm, float* __restrict__ kws, long sU, long sK)
{
  ump += (long)blockIdx.z * sU; usp += (long)blockIdx.z * sU;
  kwm += (long)blockIdx.z * sK; kws += (long)blockIdx.z * sK;
  __shared__ float pm[256], ps[256];
  const int e = blockIdx.x, t = threadIdx.x;
  const float* row = Wk + (long)e * EE;
  float am = 0.f, as = 0.f;
  for (int i = t; i < EE; i += 256) {
    float um = 0.f, us = 0.f;
    #pragma unroll
    for (int c = 0; c < 8; c++) { um += ump[(long)c * EE + i]; us += usp[(long)c * EE + i]; }
    float w = row[i];
    am += w * um;
    as += w * us;
  }
  pm[t] = am; ps[t] = as;
  __syncthreads();
  for (int s = 128; s > 0; s >>= 1) {
    if (t < s) { pm[t] += pm[t + s]; ps[t] += ps[t + s]; }
    __syncthreads();
  }
  if (t == 0) { kwm[e] = pm[0]; kws[e] = ps[0]; }
}

__global__ __launch_bounds__(256) void nb_amas(
    const float* __restrict__ Wq, const float* __restrict__ kwm, const float* __restrict__ kws,
    float* __restrict__ AmAs, long sK, long sAm)
{
  kwm += (long)blockIdx.z * sK; kws += (long)blockIdx.z * sK;
  AmAs += (long)blockIdx.z * sAm;
  __shared__ float km[64], ks[64];
  const int t = threadIdx.x;
  const int h = blockIdx.y;
  const int e = blockIdx.x * 256 + t;
  if (t < 64) { km[t] = kwm[h * 64 + t]; ks[t] = kws[h * 64 + t]; }
  __syncthreads();
  float am = 0.f, as = 0.f;
  #pragma unroll 8
  for (int d = 0; d < 64; d++) {
    float w = Wq[(long)(h * 64 + d) * EE + e];
    am += km[d] * w;
    as += ks[d] * w;
  }
  AmAs[(long)e * 32 + h]      = am;
  AmAs[(long)e * 32 + 16 + h] = as;
}

__global__ __launch_bounds__(256) void nb_musig(
    const float* __restrict__ qb, const float* __restrict__ AmAs,
    float* __restrict__ muq, float* __restrict__ sg2, long sQ, long sAm, long sMu)
{
  qb += (long)blockIdx.z * sQ; AmAs += (long)blockIdx.z * sAm;
  muq += (long)blockIdx.z * sMu; sg2 += (long)blockIdx.z * sMu;
  __shared__ float qs[EE];
  __shared__ float part[8][32];
  const int t = threadIdx.x, qrow = blockIdx.x;
  for (int i = t; i < EE; i += 256) qs[i] = qb[(long)qrow * EE + i];
  __syncthreads();
  const int o = t & 31, ch = t >> 5;
  float acc = 0.f;
  const int e0 = ch * 128;
  #pragma unroll 8
  for (int i = 0; i < 128; i++) {
    int e = e0 + i;
    acc += qs[e] * AmAs[(long)e * 32 + o];
  }
  part[ch][o] = acc;
  __syncthreads();
  if (t < 32) {
    float s = 0.f;
    #pragma unroll
    for (int c = 0; c < 8; c++) s += part[c][o];
    s *= 0.125f;
    if (o < 16) {
      muq[(long)o * QQ + qrow] = 1.f / (1.f + expf(-s));
    } else {
      float sp = (s > 20.f) ? s : log1pf(expf(s));
      sg2[(long)(o - 16) * QQ + qrow] = fmaxf(sp, 1e-4f);
    }
  }
}

// ================= ctx: 128q x 64e tile per head, 128 thr, 8x8 micro =================
__global__ __launch_bounds__(128) void nb_ctx128(
    const float* __restrict__ vals, const float* __restrict__ muq, const float* __restrict__ sg2,
    const float* __restrict__ bmu,  const float* __restrict__ bsg, float* __restrict__ ctx,
    long sV, long sMu, long sC)
{
  vals += (long)blockIdx.z * sV; ctx += (long)blockIdx.z * sC;
  muq += (long)blockIdx.z * sMu; sg2 += (long)blockIdx.z * sMu;
  __shared__ float As[32][132], Bs[32][68];     // As: r^T [n][q], Bs: vals [n][e]
  __shared__ float mu_s[128], s2_s[128];
  const int t = threadIdx.x;
  const int tx = t & 7, ty = t >> 3;
  const long q0 = (long)blockIdx.x * 128;
  const int h = blockIdx.y;
  mu_s[t] = muq[(long)h * QQ + q0 + t];
  s2_s[t] = sg2[(long)h * QQ + q0 + t];
  __syncthreads();
  float acc[8][8] = {};
  for (int n0 = 0; n0 < NB; n0 += 32) {
    #pragma unroll
    for (int i = 0; i < 4; i++) {
      int f = t + i * 128;               // 512 f4 = 32n x 16 f4
      int r = f >> 4, c4 = f & 15;
      *(float4*)&Bs[r][c4 * 4] = *(const float4*)&vals[(long)(n0 + r) * EE + h * 64 + c4 * 4];
    }
    #pragma unroll
    for (int i = 0; i < 8; i++) {
      int idx = t + i * 128;             // 1024 groups = 32n x 32 q-quads
      int n = idx >> 5, qg = idx & 31;
      float bm = bmu[n0 + n], bs = bsg[n0 + n];
      float bs2 = bs * bs;
      float4 rr;
      {
        float v0 = s2_s[qg*4+0] + bs2, d0 = mu_s[qg*4+0] - bm;
        float v1 = s2_s[qg*4+1] + bs2, d1 = mu_s[qg*4+1] - bm;
        float v2 = s2_s[qg*4+2] + bs2, d2 = mu_s[qg*4+2] - bm;
        float v3 = s2_s[qg*4+3] + bs2, d3 = mu_s[qg*4+3] - bm;
        rr.x = expf(-0.5f * d0 * d0 / v0) / sqrtf(6.283185307179586f * v0);
        rr.y = expf(-0.5f * d1 * d1 / v1) / sqrtf(6.283185307179586f * v1);
        rr.z = expf(-0.5f * d2 * d2 / v2) / sqrtf(6.283185307179586f * v2);
        rr.w = expf(-0.5f * d3 * d3 / v3) / sqrtf(6.283185307179586f * v3);
      }
      *(float4*)&As[n][qg * 4] = rr;
    }
    __syncthreads();
    #pragma unroll
    for (int kk = 0; kk < 32; kk++) {
      float4 a0 = *(const float4*)&As[kk][ty*8];
      float4 a1 = *(const float4*)&As[kk][ty*8+4];
      float4 b0 = *(const float4*)&Bs[kk][tx*8];
      float4 b1 = *(const float4*)&Bs[kk][tx*8+4];
      float ar[8] = {a0.x,a0.y,a0.z,a0.w,a1.x,a1.y,a1.z,a1.w};
      float br[8] = {b0.x,b0.y,b0.z,b0.w,b1.x,b1.y,b1.z,b1.w};
      #pragma unroll
      for (int i = 0; i < 8; i++)
        #pragma unroll
        for (int j = 0; j < 8; j++)
          acc[i][j] += ar[i] * br[j];
    }
    __syncthreads();
  }
  #pragma unroll
  for (int i = 0; i < 8; i++) {
    float4 o0 = make_float4(acc[i][0], acc[i][1], acc[i][2], acc[i][3]);
    float4 o1 = make_float4(acc[i][4], acc[i][5], acc[i][6], acc[i][7]);
    *(float4*)&ctx[(q0 + ty*8 + i) * EE + h * 64 + tx*8    ] = o0;
    *(float4*)&ctx[(q0 + ty*8 + i) * EE + h * 64 + tx*8 + 4] = o1;
  }
}

extern "C" void kernel_launch(void* const* d_in, const int* in_sizes, int n_in,
                              void* d_out, int out_size, void* d_ws, size_t ws_size,
                              hipStream_t stream) {
  const float* k   = (const float*)d_in[0];
  const float* q   = (const float*)d_in[1];
  const float* Wq  = (const float*)d_in[2];
  const float* Wk  = (const float*)d_in[3];
  const float* Wv  = (const float*)d_in[4];
  const float* Wo  = (const float*)d_in[5];
  const float* wmu = (const float*)d_in[6];
  const float* wsg = (const float*)d_in[7];
  const float* Gs  = (const float*)d_in[8];
  const float* bmu = (const float*)d_in[9];
  const float* bsg = (const float*)d_in[10];
  float* out = (float*)d_out;
  char* ws = (char*)d_ws;

  const long sBm = (long)NB * EE;      // 2 MiB
  const long sU  = 8L * EE;
  const long sK  = EE;
  const long sAm = 32L * EE;
  const long sMu = (long)HH * QQ;
  const long sQ  = (long)QQ * EE;      // 8 MiB

  if (ws_size >= (50u << 20)) {
    // ---- tier 1 ----
    // [0,32) MiB transient: BmP(16) -> valsP(16) -> ctx4(32)
    // [32,40) Bm4 | [40,48) vals4 | [48,50) smalls
    float* BmP   = (float*)(ws + 0);
    float* valsP = (float*)(ws + 0);
    float* ctx4  = (float*)(ws + 0);
    float* Bm4   = (float*)(ws + (32u << 20));
    float* vals4 = (float*)(ws + (40u << 20));
    char*  sm    = ws + (48u << 20);
    float* ump4  = (float*)(sm);                    // 128 KiB
    float* usp4  = (float*)(sm + (128u << 10));     // 128 KiB
    float* kwm4  = (float*)(sm + (256u << 10));     // 16 KiB
    float* kws4  = (float*)(sm + (272u << 10));     // 16 KiB
    float* AmAs4 = (float*)(sm + (288u << 10));     // 512 KiB
    float* muq4  = (float*)(sm + (800u << 10));     // 512 KiB
    float* sg24  = (float*)(sm + (1312u << 10));    // 512 KiB

    // st2: Bm = Gs^T @ k, split-K=2 (256 blocks)
    gemm_tn128<<<dim3(EE/128, NB/128, BB*2), 256, 0, stream>>>(
        Gs, k, BmP, NB, EE, 0L, (long)LL*EE, sBm, 2, LL/2);
    add_pairs<<<dim3(256, 1, BB), 256, 0, stream>>>(Bm4, sBm, BmP, 2*sBm, sBm);
    // st3: vals = Bm @ Wv^T, split-K=2 (256 blocks)
    gemm_nt128<<<dim3(EE/128, NB/128, BB*2), 256, 0, stream>>>(
        Bm4, Wv, valsP, EE, EE, sBm, 0L, sBm, 2, EE/2);
    add_pairs<<<dim3(256, 1, BB), 256, 0, stream>>>(vals4, sBm, valsP, 2*sBm, sBm);
    // collapsed scores chain
    nb_uvec  <<<dim3(EE/256, 8, BB),  256, 0, stream>>>(Bm4, wmu, wsg, ump4, usp4, sBm, sU);
    nb_kw    <<<dim3(EE, 1, BB),      256, 0, stream>>>(Wk, ump4, usp4, kwm4, kws4, sU, sK);
    nb_amas  <<<dim3(EE/256, HH, BB), 256, 0, stream>>>(Wq, kwm4, kws4, AmAs4, sK, sAm);
    nb_musig <<<dim3(QQ, 1, BB),      256, 0, stream>>>(q, AmAs4, muq4, sg24, sQ, sAm, sMu);
    // ctx (1024 blocks) then st7 batched (512 blocks)
    nb_ctx128<<<dim3(QQ/128, HH, BB), 128, 0, stream>>>(
        vals4, muq4, sg24, bmu, bsg, ctx4, sBm, sMu, sQ);
    gemm_nt128<<<dim3(EE/128, QQ/128, BB), 256, 0, stream>>>(
        ctx4, Wo, out, EE, EE, sQ, 0L, sQ, 1, EE);
  } else {
    // ---- tier 2 (ws >= 26 MiB, proven by round-2 run) ----
    // [0,16) BmP (in-place add -> Bm slabs at stride 2*sBm); [0,8) later ctxS
    // [16,24) vals4 | [24,26) smalls
    float* BmP   = (float*)(ws + 0);
    float* ctxS  = (float*)(ws + 0);
    float* vals4 = (float*)(ws + (16u << 20));
    char*  sm    = ws + (24u << 20);
    float* ump4  = (float*)(sm);
    float* usp4  = (float*)(sm + (128u << 10));
    float* kwm4  = (float*)(sm + (256u << 10));
    float* kws4  = (float*)(sm + (272u << 10));
    float* AmAs4 = (float*)(sm + (288u << 10));
    float* muq4  = (float*)(sm + (800u << 10));
    float* sg24  = (float*)(sm + (1312u << 10));

    gemm_tn128<<<dim3(EE/128, NB/128, BB*2), 256, 0, stream>>>(
        Gs, k, BmP, NB, EE, 0L, (long)LL*EE, sBm, 2, LL/2);
    add_pairs<<<dim3(256, 1, BB), 256, 0, stream>>>(BmP, 2*sBm, BmP, 2*sBm, sBm);
    gemm_nt128<<<dim3(EE/128, NB/128, BB), 256, 0, stream>>>(
        BmP, Wv, vals4, EE, EE, 2*sBm, 0L, sBm, 1, EE);
    nb_uvec  <<<dim3(EE/256, 8, BB),  256, 0, stream>>>(BmP, wmu, wsg, ump4, usp4, 2*sBm, sU);
    nb_kw    <<<dim3(EE, 1, BB),      256, 0, stream>>>(Wk, ump4, usp4, kwm4, kws4, sU, sK);
    nb_amas  <<<dim3(EE/256, HH, BB), 256, 0, stream>>>(Wq, kwm4, kws4, AmAs4, sK, sAm);
    nb_musig <<<dim3(QQ, 1, BB),      256, 0, stream>>>(q, AmAs4, muq4, sg24, sQ, sAm, sMu);
    for (int b = 0; b < BB; b++) {
      nb_ctx128<<<dim3(QQ/128, HH, 1), 128, 0, stream>>>(
          vals4 + (long)b*sBm, muq4 + (long)b*sMu, sg24 + (long)b*sMu,
          bmu, bsg, ctxS, 0L, 0L, 0L);
      gemm_nt64<<<dim3(EE/64, QQ/64, 1), 256, 0, stream>>>(
          ctxS, Wo, out + (long)b*sQ, QQ, EE, EE, 0L, 0L, 0L);
    }
  }
  (void)in_sizes; (void)n_in; (void)out_size;
}